// Round 5
// baseline (68.870 us; speedup 1.0000x reference)
//
#include <hip/hip_runtime.h>

// SpatioTemporalGAT  (N=4096, F=64, H=64, K=2 heads, O=32; temporal input unused)
//
// R4 lesson: grid=256 blocks on 256 CUs -> 1 block/CU, so gat_attn's in-block
// adj->ballot phase (~10us, mem-only, latency-chained at 4B/lane) serialized
// with the main loop on every CU; and the per-j VALU chain (v_exp at 1/4 rate,
// 4-op manual bf16 pack) kept VALU issue at 13.4us with 70% stall.
// Fixes: (1) adj->bits precomputed in the whole-chip prep kernel; (2) exp
// removed from the hot loop via factorization exp(lrelu(sd+ss)) =
// pp>1 ? e1p*e1q : e2p*e2q (e1=exp(s), e2=exp(0.2s) per node, exact since exp
// is monotone and both branches equal 1 at the boundary); (3) bf16 pack via
// v_cvt_pk_bf16_f32 (2 vals/op).
//
// prep_all  — merged grid: [0,64) Wh GEMM + e1/e2 node factors + whB B-frag
//             store; [64,169) LSTM/fc weight packing; [169,1193) adj->bitmask
//             (ballot, coalesced, adj leaves HBM exactly once chip-wide).
// gat_attn  — stage 8KB bits; fused masked-softmax+PV via mfma 16x16x32 bf16
//             (no max-sub: logits bounded ~2); combine 16 wave partials;
//             fused LSTM gates GEMM + nonlinearity + fc GEMM epilogue.

#define NN 4096

typedef __attribute__((ext_vector_type(8))) short bf16x8;
typedef __attribute__((ext_vector_type(4))) float f32x4;

__device__ inline unsigned short bf_rne(float f) {
    unsigned u = __float_as_uint(f);
    u += 0x7fffu + ((u >> 16) & 1u);
    return (unsigned short)(u >> 16);
}

__device__ inline unsigned cvt_pk_bf16(float lo, float hi) {
    unsigned r;
    asm("v_cvt_pk_bf16_f32 %0, %1, %2" : "=v"(r) : "v"(lo), "v"(hi));
    return r;
}

__device__ inline float sigf(float x) { return 1.f / (1.f + __expf(-x)); }

__global__ __launch_bounds__(256) void prep_all(
    const float* __restrict__ X, const float* __restrict__ Wg,
    const float* __restrict__ a_src, const float* __restrict__ a_dst,
    const int* __restrict__ adj, const float* __restrict__ W_ih,
    const float* __restrict__ b_ih, const float* __restrict__ b_hh,
    const float* __restrict__ fc_W,
    unsigned short* __restrict__ whB, float* __restrict__ e1s,
    float* __restrict__ e2s, float* __restrict__ e1d, float* __restrict__ e2d,
    unsigned long long* __restrict__ adjbits,
    unsigned short* __restrict__ Wpk, unsigned short* __restrict__ fcb,
    float* __restrict__ biasg)
{
    __shared__ float X_lds[64][64];
    __shared__ float Wh_lds[64][65];
    __shared__ float spart[64][4][2];
    const int t = threadIdx.x;
    const int bid = blockIdx.x;

    if (bid >= 169) {
        // ---- adj -> bitmask: 1024 blocks x 4 waves, 64 words each ----
        const int wave = t >> 6, lane = t & 63;
        const long wid = (long)(bid - 169) * 4 + wave;   // 0..4095
#pragma unroll 4
        for (int it = 0; it < 64; ++it) {
            const long w = wid * 64 + it;
            const int v = adj[w * 64 + lane];
            const unsigned long long b = __ballot(v != 0);
            if (lane == 0) adjbits[w] = b;
        }
        return;
    }
    if (bid >= 64) {
        // ---- weight packing (was convert_w) ----
        const int idx = (bid - 64) * 256 + t;
        if (idx < 24576) {
            const int j = idx & 7, lane = (idx >> 3) & 63;
            const int k0 = (idx >> 9) & 3, tt = idx >> 11;
            const int jj = tt * 16 + (lane & 15);
            const int m = k0 * 32 + (lane >> 4) * 8 + j;
            const int sr = (jj < 64) ? jj : 64 + jj;        // skip dead f rows
            Wpk[idx] = bf_rne(W_ih[sr * 128 + m]);
        } else if (idx < 26624) {
            const int o = idx - 24576;                      // fc frag: 2 tiles
            const int j = o & 7, lane = (o >> 3) & 63;
            const int k0 = (o >> 9) & 1, tt = o >> 10;
            const int row = tt * 16 + (lane & 15);
            const int m = k0 * 32 + (lane >> 4) * 8 + j;
            fcb[o] = bf_rne(fc_W[row * 64 + m]);
        } else if (idx < 26816) {
            const int j = idx - 26624;
            const int sr = (j < 64) ? j : 64 + j;
            biasg[j] = b_ih[sr] + b_hh[sr];
        }
        return;
    }

    // ---- Wh GEMM + e-factors + whB B-frag store (was gat_prep) ----
    const int n0 = bid * 64;
#pragma unroll
    for (int i = 0; i < 16; ++i) {
        int idx = t + i * 256;
        X_lds[idx >> 6][idx & 63] = X[n0 * 64 + idx];
    }
    __syncthreads();
    const int h = t & 63, rg = t >> 6;
    for (int k = 0; k < 2; ++k) {
        float acc[16];
#pragma unroll
        for (int r = 0; r < 16; ++r) acc[r] = 0.f;
        for (int f0 = 0; f0 < 64; f0 += 4) {
            const float4 w4 = *(const float4*)&Wg[(k * 64 + h) * 64 + f0];
#pragma unroll
            for (int r = 0; r < 16; ++r) {
                const float4 x4 = *(const float4*)&X_lds[rg * 16 + r][f0];
                acc[r] += w4.x * x4.x + w4.y * x4.y + w4.z * x4.z + w4.w * x4.w;
            }
        }
        if (k) __syncthreads();
#pragma unroll
        for (int r = 0; r < 16; ++r) Wh_lds[rg * 16 + r][h] = acc[r];
        __syncthreads();
        {   // per-node logit terms (partial over 16 h each)
            const int r = t & 63, qa = t >> 6;
            float ps = 0.f, pd = 0.f;
#pragma unroll
            for (int i = 0; i < 16; ++i) {
                const int hh = qa * 16 + i;
                const float v = Wh_lds[r][hh];
                ps += v * a_src[k * 64 + hh];
                pd += v * a_dst[k * 64 + hh];
            }
            spart[r][qa][0] = ps;
            spart[r][qa][1] = pd;
        }
        {   // bf16 store in MFMA B-frag order:
            // flat = ((k*4+f)*128+qb)*512 + (qg*16+n)*8 + j
#pragma unroll
            for (int pid = t; pid < 512; pid += 256) {
                const int n = pid & 15, qg = (pid >> 4) & 3;
                const int qb_loc = (pid >> 6) & 1, f = pid >> 7;
                const int qb = (n0 >> 5) + qb_loc;
                unsigned pk[4];
#pragma unroll
                for (int i = 0; i < 4; ++i) {
                    const int r = qb_loc * 32 + qg * 8 + 2 * i;
                    unsigned lo = bf_rne(Wh_lds[r][f * 16 + n]);
                    unsigned hi = bf_rne(Wh_lds[r + 1][f * 16 + n]);
                    pk[i] = lo | (hi << 16);
                }
                uint4* dst = (uint4*)&whB[(((k * 4 + f) * 128 + qb) * 512) + (qg * 16 + n) * 8];
                *dst = make_uint4(pk[0], pk[1], pk[2], pk[3]);
            }
        }
        __syncthreads();
        if (t < 64) {
            float s0 = spart[t][0][0] + spart[t][1][0] + spart[t][2][0] + spart[t][3][0];
            float s1 = spart[t][0][1] + spart[t][1][1] + spart[t][2][1] + spart[t][3][1];
            e1s[k * NN + n0 + t] = __expf(s0);
            e2s[k * NN + n0 + t] = __expf(0.2f * s0);
            e1d[k * NN + n0 + t] = __expf(s1);
            e2d[k * NN + n0 + t] = __expf(0.2f * s1);
        }
    }
}

__global__ __launch_bounds__(1024) void gat_attn(
    const unsigned long long* __restrict__ adjbits,
    const unsigned short* __restrict__ whB,
    const float* __restrict__ e1s, const float* __restrict__ e2s,
    const float* __restrict__ e1d, const float* __restrict__ e2d,
    const unsigned short* __restrict__ Wpk, const unsigned short* __restrict__ fcb,
    const float* __restrict__ biasg, const float* __restrict__ fc_b,
    float* __restrict__ out)
{
    __shared__ float S_all[16][2][16][64];              // 128 KB wave partials
    __shared__ float z_all[16][2][16];                  // 2 KB
    __shared__ unsigned long long bits_lds[16][65];     // 8.3 KB adj bits (+pad)
    // post-combine aliases into dead S_all space:
    unsigned short* h_lds = (unsigned short*)&S_all[0][0][0][0];      // [16][136] bf16
    float* gate_lds = (float*)((char*)&S_all[0][0][0][0] + 4608);     // [3][16][68] f32

    const int tid = threadIdx.x;
    const int wave = tid >> 6, lane = tid & 63;
    const int rloc = lane & 15, qg = lane >> 4;
    const int p0 = blockIdx.x * 16;
    const int p = p0 + rloc;

    // ---- stage 16 rows x 64 words of precomputed adjacency bits ----
    bits_lds[tid >> 6][tid & 63] = adjbits[(long)(p0 + (tid >> 6)) * 64 + (tid & 63)];
    __syncthreads();

    // per-lane row factors
    const float e1p0 = e1d[p], e2p0 = e2d[p];
    const float e1p1 = e1d[NN + p], e2p1 = e2d[NN + p];
    const unsigned short* __restrict__ whB_l = whB + lane * 8;

    f32x4 acc[2][4];
#pragma unroll
    for (int k = 0; k < 2; ++k)
#pragma unroll
        for (int f = 0; f < 4; ++f)
            acc[k][f] = (f32x4){0.f, 0.f, 0.f, 0.f};
    float z0 = 0.f, z1 = 0.f;

    const int qbase = wave * 256;   // each wave owns a 256-wide q slice
    for (int chunk = 0; chunk < 4; ++chunk) {
        const unsigned long long bw = bits_lds[rloc][wave * 4 + chunk];
#pragma unroll
        for (int kk = 0; kk < 2; ++kk) {       // two K=32 steps per 64-q chunk
            const int q0 = qbase + chunk * 64 + kk * 32 + qg * 8;
            const int qb = wave * 8 + chunk * 2 + kk;
            const unsigned byte8 = ((unsigned)(bw >> (kk * 32)) >> (qg * 8)) & 0xffu;
            // q-side factors (L2-hot broadcast arrays)
            const float4 qa0 = *(const float4*)(e1s + q0);
            const float4 qa1 = *(const float4*)(e1s + q0 + 4);
            const float4 qb0 = *(const float4*)(e2s + q0);
            const float4 qb1 = *(const float4*)(e2s + q0 + 4);
            const float4 qc0 = *(const float4*)(e1s + NN + q0);
            const float4 qc1 = *(const float4*)(e1s + NN + q0 + 4);
            const float4 qd0 = *(const float4*)(e2s + NN + q0);
            const float4 qd1 = *(const float4*)(e2s + NN + q0 + 4);
            const float q1v0[8] = {qa0.x, qa0.y, qa0.z, qa0.w, qa1.x, qa1.y, qa1.z, qa1.w};
            const float q2v0[8] = {qb0.x, qb0.y, qb0.z, qb0.w, qb1.x, qb1.y, qb1.z, qb1.w};
            const float q1v1[8] = {qc0.x, qc0.y, qc0.z, qc0.w, qc1.x, qc1.y, qc1.z, qc1.w};
            const float q2v1[8] = {qd0.x, qd0.y, qd0.z, qd0.w, qd1.x, qd1.y, qd1.z, qd1.w};
            float w0a[8], w1a[8];
#pragma unroll
            for (int j = 0; j < 8; ++j) {
                const bool on = (byte8 & (1u << j)) != 0u;
                // w = exp(lrelu(sd+ss)) ; pp=exp(sd+ss) ; pp>1 <=> sd+ss>0
                const float pp0 = e1p0 * q1v0[j];
                float w0 = pp0 > 1.f ? pp0 : e2p0 * q2v0[j];
                w0 = on ? w0 : 0.f;
                z0 += w0;
                w0a[j] = w0;
                const float pp1 = e1p1 * q1v1[j];
                float w1 = pp1 > 1.f ? pp1 : e2p1 * q2v1[j];
                w1 = on ? w1 : 0.f;
                z1 += w1;
                w1a[j] = w1;
            }
            union { bf16x8 v; unsigned w[4]; } fa0, fa1;
#pragma unroll
            for (int i = 0; i < 4; ++i) {
                fa0.w[i] = cvt_pk_bf16(w0a[2 * i], w0a[2 * i + 1]);
                fa1.w[i] = cvt_pk_bf16(w1a[2 * i], w1a[2 * i + 1]);
            }
#pragma unroll
            for (int f = 0; f < 4; ++f) {
                const bf16x8 b0 = *(const bf16x8*)(whB_l + ((f * 128 + qb) << 9));
                acc[0][f] = __builtin_amdgcn_mfma_f32_16x16x32_bf16(fa0.v, b0, acc[0][f], 0, 0, 0);
                const bf16x8 b1 = *(const bf16x8*)(whB_l + (((4 + f) * 128 + qb) << 9));
                acc[1][f] = __builtin_amdgcn_mfma_f32_16x16x32_bf16(fa1.v, b1, acc[1][f], 0, 0, 0);
            }
        }
    }
    // z: sum the 4 q-groups (lanes l, l^16, l^32, l^48 share a row)
    z0 += __shfl_xor(z0, 16); z0 += __shfl_xor(z0, 32);
    z1 += __shfl_xor(z1, 16); z1 += __shfl_xor(z1, 32);
    if (lane < 16) { z_all[wave][0][lane] = z0; z_all[wave][1][lane] = z1; }
    // D-frag layout: row=(l>>4)*4+j, col=l&15
#pragma unroll
    for (int k = 0; k < 2; ++k)
#pragma unroll
        for (int f = 0; f < 4; ++f)
#pragma unroll
            for (int j = 0; j < 4; ++j)
                S_all[wave][k][qg * 4 + j][f * 16 + rloc] = acc[k][f][j];
    __syncthreads();
    // combine 16 wave-partials, normalize, elu -> registers
    float vreg[2]; int vk[2], vr[2], vh[2];
#pragma unroll
    for (int i = 0; i < 2; ++i) {
        const int idx = tid + i * 1024;
        const int k = idx >> 10, rr = (idx >> 6) & 15, hh = idx & 63;
        float s = 0.f, z = 0.f;
#pragma unroll
        for (int w = 0; w < 16; ++w) {
            s += S_all[w][k][rr][hh];
            z += z_all[w][k][rr];
        }
        float v = s / z;
        vreg[i] = v > 0.f ? v : expm1f(v);
        vk[i] = k; vr[i] = rr; vh[i] = hh;
    }
    __syncthreads();    // all S_all reads done; safe to reuse as h_lds/gate_lds
    // h tile bf16 [node][k*64+h], padded row 136 (272B, 16B-aligned rows)
#pragma unroll
    for (int i = 0; i < 2; ++i)
        h_lds[vr[i] * 136 + vk[i] * 64 + vh[i]] = bf_rne(vreg[i]);
    __syncthreads();

    // ---- fused LSTM gates GEMM: 12 waves, one 16-col gate tile each ----
    const int c = lane & 15, g4 = lane >> 4;
    if (wave < 12) {
        const int t = wave;
        f32x4 ga = (f32x4){0.f, 0.f, 0.f, 0.f};
#pragma unroll
        for (int k0 = 0; k0 < 4; ++k0) {
            const bf16x8 a = *(const bf16x8*)&h_lds[c * 136 + k0 * 32 + g4 * 8];
            const bf16x8 b = *(const bf16x8*)&Wpk[((t * 4 + k0) * 64 + lane) * 8];
            ga = __builtin_amdgcn_mfma_f32_16x16x32_bf16(a, b, ga, 0, 0, 0);
        }
        const float bb = biasg[t * 16 + c];
#pragma unroll
        for (int j = 0; j < 4; ++j)
            gate_lds[(t >> 2) * 1088 + (g4 * 4 + j) * 68 + (t & 3) * 16 + c] = ga[j] + bb;
    }
    __syncthreads();
    // ---- LSTM nonlinearity: ht = sig(o)*tanh(sig(i)*tanh(g)) ----
    {
        const int n = tid >> 6, hh = tid & 63;
        const float iv = gate_lds[n * 68 + hh];
        const float gv = gate_lds[1088 + n * 68 + hh];
        const float ov = gate_lds[2176 + n * 68 + hh];
        const float cv = sigf(iv) * tanhf(gv);
        const float htv = sigf(ov) * tanhf(cv);
        __syncthreads();
        h_lds[n * 136 + hh] = bf_rne(htv);   // reuse h_lds (gates consumed h)
    }
    __syncthreads();
    // ---- fc GEMM: waves 0,1 -> out[16 nodes][32] ----
    if (wave < 2) {
        const int t2 = wave;
        f32x4 fa = (f32x4){0.f, 0.f, 0.f, 0.f};
#pragma unroll
        for (int k0 = 0; k0 < 2; ++k0) {
            const bf16x8 a = *(const bf16x8*)&h_lds[c * 136 + k0 * 32 + g4 * 8];
            const bf16x8 b = *(const bf16x8*)&fcb[((t2 * 2 + k0) * 64 + lane) * 8];
            fa = __builtin_amdgcn_mfma_f32_16x16x32_bf16(a, b, fa, 0, 0, 0);
        }
        const float fb = fc_b[t2 * 16 + c];
#pragma unroll
        for (int j = 0; j < 4; ++j)
            out[(p0 + g4 * 4 + j) * 32 + t2 * 16 + c] = fa[j] + fb;
    }
}

extern "C" void kernel_launch(void* const* d_in, const int* in_sizes, int n_in,
                              void* d_out, int out_size, void* d_ws, size_t ws_size,
                              hipStream_t stream) {
    const float* X     = (const float*)d_in[0];
    const int*   adj   = (const int*)d_in[1];
    // d_in[2] temporal_features: unused by the reference
    const float* Wg    = (const float*)d_in[3];
    const float* a_src = (const float*)d_in[4];
    const float* a_dst = (const float*)d_in[5];
    const float* W_ih  = (const float*)d_in[6];
    // d_in[7] W_hh: unused (h0 == 0)
    const float* b_ih  = (const float*)d_in[8];
    const float* b_hh  = (const float*)d_in[9];
    const float* fc_W  = (const float*)d_in[10];
    const float* fc_b  = (const float*)d_in[11];
    float* out = (float*)d_out;

    char* ws = (char*)d_ws;
    unsigned short* whB = (unsigned short*)ws;                       // 1 MB
    float* e1s = (float*)(ws + (1 << 20));                           // 32 KB
    float* e2s = (float*)(ws + (1 << 20) + (32 << 10));              // 32 KB
    float* e1d = (float*)(ws + (1 << 20) + (64 << 10));              // 32 KB
    float* e2d = (float*)(ws + (1 << 20) + (96 << 10));              // 32 KB
    unsigned long long* adjbits = (unsigned long long*)(ws + (1 << 20) + (128 << 10)); // 2 MB
    char* ws2 = ws + (3 << 20) + (128 << 10);
    unsigned short* Wpk = (unsigned short*)ws2;                      // 48 KB
    unsigned short* fcb = (unsigned short*)(ws2 + (48 << 10));       // 4 KB
    float* biasg = (float*)(ws2 + (52 << 10));                       // 768 B

    hipLaunchKernelGGL(prep_all, dim3(1193), dim3(256), 0, stream,
                       X, Wg, a_src, a_dst, adj, W_ih, b_ih, b_hh, fc_W,
                       whB, e1s, e2s, e1d, e2d, adjbits, Wpk, fcb, biasg);
    hipLaunchKernelGGL(gat_attn, dim3(256), dim3(1024), 0, stream,
                       adjbits, whB, e1s, e2s, e1d, e2d, Wpk, fcb, biasg, fc_b, out);
}

// Round 6
// 52.489 us; speedup vs baseline: 1.3121x; 1.3121x over previous
//
#include <hip/hip_runtime.h>

// SpatioTemporalGAT  (N=4096, F=64, H=64, K=2 heads, O=32; temporal input unused)
//
// R5 lesson: the adj->bits loop stored to global (exec-masked, lane 0) EVERY
// iteration; the store shares vmcnt with the loads, the conservative waitcnt
// before each ballot drained it -> pipeline depth ~1 -> 60us latency-bound
// (HBM 610 GB/s, VALU 3.5%). R4's in-block version (register accumulate via
// `if (lane==it) myw=bal`, single store at end) had no such stall.
// Fix: register-accumulate ballot + ONE coalesced 512B store per wave-row,
// unroll 8 (8x256B in flight/wave; 16 waves/CU -> 32KB/CU >> BW*lat ~9KB).
//
// prep_all  — merged grid: [0,64) Wh GEMM + e1/e2 node factors + whB B-frag
//             store; [64,169) LSTM/fc weight packing; [169,1193) adj->bitmask.
// gat_attn  — stage 8KB bits; fused masked-softmax+PV via mfma 16x16x32 bf16
//             (exp-free hot loop: w = pp>1 ? e1p*e1q : e2p*e2q); combine 16
//             wave partials; fused LSTM gates GEMM + nonlinearity + fc GEMM.

#define NN 4096

typedef __attribute__((ext_vector_type(8))) short bf16x8;
typedef __attribute__((ext_vector_type(4))) float f32x4;

__device__ inline unsigned short bf_rne(float f) {
    unsigned u = __float_as_uint(f);
    u += 0x7fffu + ((u >> 16) & 1u);
    return (unsigned short)(u >> 16);
}

__device__ inline unsigned cvt_pk_bf16(float lo, float hi) {
    unsigned r;
    asm("v_cvt_pk_bf16_f32 %0, %1, %2" : "=v"(r) : "v"(lo), "v"(hi));
    return r;
}

__device__ inline float sigf(float x) { return 1.f / (1.f + __expf(-x)); }

__global__ __launch_bounds__(256) void prep_all(
    const float* __restrict__ X, const float* __restrict__ Wg,
    const float* __restrict__ a_src, const float* __restrict__ a_dst,
    const int* __restrict__ adj, const float* __restrict__ W_ih,
    const float* __restrict__ b_ih, const float* __restrict__ b_hh,
    const float* __restrict__ fc_W,
    unsigned short* __restrict__ whB, float* __restrict__ e1s,
    float* __restrict__ e2s, float* __restrict__ e1d, float* __restrict__ e2d,
    unsigned long long* __restrict__ adjbits,
    unsigned short* __restrict__ Wpk, unsigned short* __restrict__ fcb,
    float* __restrict__ biasg)
{
    __shared__ float X_lds[64][64];
    __shared__ float Wh_lds[64][65];
    __shared__ float spart[64][4][2];
    const int t = threadIdx.x;
    const int bid = blockIdx.x;

    if (bid >= 169) {
        // ---- adj -> bitmask: 1024 blocks x 4 waves, one row per wave ----
        // Register-accumulated ballots; single coalesced 512B store per wave.
        const int wave = t >> 6, lane = t & 63;
        const long row = (long)(bid - 169) * 4 + wave;   // 0..4095
        const int* __restrict__ arow = adj + row * NN;
        unsigned long long myw = 0ull;
#pragma unroll 8
        for (int it = 0; it < 64; ++it) {
            const int v = arow[it * 64 + lane];
            const unsigned long long b = __ballot(v != 0);
            if (lane == it) myw = b;       // lane l keeps word l (cndmask, no store)
        }
        adjbits[row * 64 + lane] = myw;    // coalesced
        return;
    }
    if (bid >= 64) {
        // ---- weight packing ----
        const int idx = (bid - 64) * 256 + t;
        if (idx < 24576) {
            const int j = idx & 7, lane = (idx >> 3) & 63;
            const int k0 = (idx >> 9) & 3, tt = idx >> 11;
            const int jj = tt * 16 + (lane & 15);
            const int m = k0 * 32 + (lane >> 4) * 8 + j;
            const int sr = (jj < 64) ? jj : 64 + jj;        // skip dead f rows
            Wpk[idx] = bf_rne(W_ih[sr * 128 + m]);
        } else if (idx < 26624) {
            const int o = idx - 24576;                      // fc frag: 2 tiles
            const int j = o & 7, lane = (o >> 3) & 63;
            const int k0 = (o >> 9) & 1, tt = o >> 10;
            const int row = tt * 16 + (lane & 15);
            const int m = k0 * 32 + (lane >> 4) * 8 + j;
            fcb[o] = bf_rne(fc_W[row * 64 + m]);
        } else if (idx < 26816) {
            const int j = idx - 26624;
            const int sr = (j < 64) ? j : 64 + j;
            biasg[j] = b_ih[sr] + b_hh[sr];
        }
        return;
    }

    // ---- Wh GEMM + e-factors + whB B-frag store ----
    const int n0 = bid * 64;
#pragma unroll
    for (int i = 0; i < 16; ++i) {
        int idx = t + i * 256;
        X_lds[idx >> 6][idx & 63] = X[n0 * 64 + idx];
    }
    __syncthreads();
    const int h = t & 63, rg = t >> 6;
    for (int k = 0; k < 2; ++k) {
        float acc[16];
#pragma unroll
        for (int r = 0; r < 16; ++r) acc[r] = 0.f;
        for (int f0 = 0; f0 < 64; f0 += 4) {
            const float4 w4 = *(const float4*)&Wg[(k * 64 + h) * 64 + f0];
#pragma unroll
            for (int r = 0; r < 16; ++r) {
                const float4 x4 = *(const float4*)&X_lds[rg * 16 + r][f0];
                acc[r] += w4.x * x4.x + w4.y * x4.y + w4.z * x4.z + w4.w * x4.w;
            }
        }
        if (k) __syncthreads();
#pragma unroll
        for (int r = 0; r < 16; ++r) Wh_lds[rg * 16 + r][h] = acc[r];
        __syncthreads();
        {   // per-node logit terms (partial over 16 h each)
            const int r = t & 63, qa = t >> 6;
            float ps = 0.f, pd = 0.f;
#pragma unroll
            for (int i = 0; i < 16; ++i) {
                const int hh = qa * 16 + i;
                const float v = Wh_lds[r][hh];
                ps += v * a_src[k * 64 + hh];
                pd += v * a_dst[k * 64 + hh];
            }
            spart[r][qa][0] = ps;
            spart[r][qa][1] = pd;
        }
        {   // bf16 store in MFMA B-frag order:
            // flat = ((k*4+f)*128+qb)*512 + (qg*16+n)*8 + j
#pragma unroll
            for (int pid = t; pid < 512; pid += 256) {
                const int n = pid & 15, qg = (pid >> 4) & 3;
                const int qb_loc = (pid >> 6) & 1, f = pid >> 7;
                const int qb = (n0 >> 5) + qb_loc;
                unsigned pk[4];
#pragma unroll
                for (int i = 0; i < 4; ++i) {
                    const int r = qb_loc * 32 + qg * 8 + 2 * i;
                    unsigned lo = bf_rne(Wh_lds[r][f * 16 + n]);
                    unsigned hi = bf_rne(Wh_lds[r + 1][f * 16 + n]);
                    pk[i] = lo | (hi << 16);
                }
                uint4* dst = (uint4*)&whB[(((k * 4 + f) * 128 + qb) * 512) + (qg * 16 + n) * 8];
                *dst = make_uint4(pk[0], pk[1], pk[2], pk[3]);
            }
        }
        __syncthreads();
        if (t < 64) {
            float s0 = spart[t][0][0] + spart[t][1][0] + spart[t][2][0] + spart[t][3][0];
            float s1 = spart[t][0][1] + spart[t][1][1] + spart[t][2][1] + spart[t][3][1];
            e1s[k * NN + n0 + t] = __expf(s0);
            e2s[k * NN + n0 + t] = __expf(0.2f * s0);
            e1d[k * NN + n0 + t] = __expf(s1);
            e2d[k * NN + n0 + t] = __expf(0.2f * s1);
        }
    }
}

__global__ __launch_bounds__(1024) void gat_attn(
    const unsigned long long* __restrict__ adjbits,
    const unsigned short* __restrict__ whB,
    const float* __restrict__ e1s, const float* __restrict__ e2s,
    const float* __restrict__ e1d, const float* __restrict__ e2d,
    const unsigned short* __restrict__ Wpk, const unsigned short* __restrict__ fcb,
    const float* __restrict__ biasg, const float* __restrict__ fc_b,
    float* __restrict__ out)
{
    __shared__ float S_all[16][2][16][64];              // 128 KB wave partials
    __shared__ float z_all[16][2][16];                  // 2 KB
    __shared__ unsigned long long bits_lds[16][65];     // 8.3 KB adj bits (+pad)
    // post-combine aliases into dead S_all space:
    unsigned short* h_lds = (unsigned short*)&S_all[0][0][0][0];      // [16][136] bf16
    float* gate_lds = (float*)((char*)&S_all[0][0][0][0] + 4608);     // [3][16][68] f32

    const int tid = threadIdx.x;
    const int wave = tid >> 6, lane = tid & 63;
    const int rloc = lane & 15, qg = lane >> 4;
    const int p0 = blockIdx.x * 16;
    const int p = p0 + rloc;

    // ---- stage 16 rows x 64 words of precomputed adjacency bits ----
    bits_lds[tid >> 6][tid & 63] = adjbits[(long)(p0 + (tid >> 6)) * 64 + (tid & 63)];
    __syncthreads();

    // per-lane row factors
    const float e1p0 = e1d[p], e2p0 = e2d[p];
    const float e1p1 = e1d[NN + p], e2p1 = e2d[NN + p];
    const unsigned short* __restrict__ whB_l = whB + lane * 8;

    f32x4 acc[2][4];
#pragma unroll
    for (int k = 0; k < 2; ++k)
#pragma unroll
        for (int f = 0; f < 4; ++f)
            acc[k][f] = (f32x4){0.f, 0.f, 0.f, 0.f};
    float z0 = 0.f, z1 = 0.f;

    const int qbase = wave * 256;   // each wave owns a 256-wide q slice
    for (int chunk = 0; chunk < 4; ++chunk) {
        const unsigned long long bw = bits_lds[rloc][wave * 4 + chunk];
#pragma unroll
        for (int kk = 0; kk < 2; ++kk) {       // two K=32 steps per 64-q chunk
            const int q0 = qbase + chunk * 64 + kk * 32 + qg * 8;
            const int qb = wave * 8 + chunk * 2 + kk;
            const unsigned byte8 = ((unsigned)(bw >> (kk * 32)) >> (qg * 8)) & 0xffu;
            // q-side factors (L2-hot broadcast arrays)
            const float4 qa0 = *(const float4*)(e1s + q0);
            const float4 qa1 = *(const float4*)(e1s + q0 + 4);
            const float4 qb0 = *(const float4*)(e2s + q0);
            const float4 qb1 = *(const float4*)(e2s + q0 + 4);
            const float4 qc0 = *(const float4*)(e1s + NN + q0);
            const float4 qc1 = *(const float4*)(e1s + NN + q0 + 4);
            const float4 qd0 = *(const float4*)(e2s + NN + q0);
            const float4 qd1 = *(const float4*)(e2s + NN + q0 + 4);
            const float q1v0[8] = {qa0.x, qa0.y, qa0.z, qa0.w, qa1.x, qa1.y, qa1.z, qa1.w};
            const float q2v0[8] = {qb0.x, qb0.y, qb0.z, qb0.w, qb1.x, qb1.y, qb1.z, qb1.w};
            const float q1v1[8] = {qc0.x, qc0.y, qc0.z, qc0.w, qc1.x, qc1.y, qc1.z, qc1.w};
            const float q2v1[8] = {qd0.x, qd0.y, qd0.z, qd0.w, qd1.x, qd1.y, qd1.z, qd1.w};
            float w0a[8], w1a[8];
#pragma unroll
            for (int j = 0; j < 8; ++j) {
                const bool on = (byte8 & (1u << j)) != 0u;
                // w = exp(lrelu(sd+ss)) ; pp=exp(sd+ss) ; pp>1 <=> sd+ss>0
                const float pp0 = e1p0 * q1v0[j];
                float w0 = pp0 > 1.f ? pp0 : e2p0 * q2v0[j];
                w0 = on ? w0 : 0.f;
                z0 += w0;
                w0a[j] = w0;
                const float pp1 = e1p1 * q1v1[j];
                float w1 = pp1 > 1.f ? pp1 : e2p1 * q2v1[j];
                w1 = on ? w1 : 0.f;
                z1 += w1;
                w1a[j] = w1;
            }
            union { bf16x8 v; unsigned w[4]; } fa0, fa1;
#pragma unroll
            for (int i = 0; i < 4; ++i) {
                fa0.w[i] = cvt_pk_bf16(w0a[2 * i], w0a[2 * i + 1]);
                fa1.w[i] = cvt_pk_bf16(w1a[2 * i], w1a[2 * i + 1]);
            }
#pragma unroll
            for (int f = 0; f < 4; ++f) {
                const bf16x8 b0 = *(const bf16x8*)(whB_l + ((f * 128 + qb) << 9));
                acc[0][f] = __builtin_amdgcn_mfma_f32_16x16x32_bf16(fa0.v, b0, acc[0][f], 0, 0, 0);
                const bf16x8 b1 = *(const bf16x8*)(whB_l + (((4 + f) * 128 + qb) << 9));
                acc[1][f] = __builtin_amdgcn_mfma_f32_16x16x32_bf16(fa1.v, b1, acc[1][f], 0, 0, 0);
            }
        }
    }
    // z: sum the 4 q-groups (lanes l, l^16, l^32, l^48 share a row)
    z0 += __shfl_xor(z0, 16); z0 += __shfl_xor(z0, 32);
    z1 += __shfl_xor(z1, 16); z1 += __shfl_xor(z1, 32);
    if (lane < 16) { z_all[wave][0][lane] = z0; z_all[wave][1][lane] = z1; }
    // D-frag layout: row=(l>>4)*4+j, col=l&15
#pragma unroll
    for (int k = 0; k < 2; ++k)
#pragma unroll
        for (int f = 0; f < 4; ++f)
#pragma unroll
            for (int j = 0; j < 4; ++j)
                S_all[wave][k][qg * 4 + j][f * 16 + rloc] = acc[k][f][j];
    __syncthreads();
    // combine 16 wave-partials, normalize, elu -> registers
    float vreg[2]; int vk[2], vr[2], vh[2];
#pragma unroll
    for (int i = 0; i < 2; ++i) {
        const int idx = tid + i * 1024;
        const int k = idx >> 10, rr = (idx >> 6) & 15, hh = idx & 63;
        float s = 0.f, z = 0.f;
#pragma unroll
        for (int w = 0; w < 16; ++w) {
            s += S_all[w][k][rr][hh];
            z += z_all[w][k][rr];
        }
        float v = s / z;
        vreg[i] = v > 0.f ? v : expm1f(v);
        vk[i] = k; vr[i] = rr; vh[i] = hh;
    }
    __syncthreads();    // all S_all reads done; safe to reuse as h_lds/gate_lds
    // h tile bf16 [node][k*64+h], padded row 136 (272B, 16B-aligned rows)
#pragma unroll
    for (int i = 0; i < 2; ++i)
        h_lds[vr[i] * 136 + vk[i] * 64 + vh[i]] = bf_rne(vreg[i]);
    __syncthreads();

    // ---- fused LSTM gates GEMM: 12 waves, one 16-col gate tile each ----
    const int c = lane & 15, g4 = lane >> 4;
    if (wave < 12) {
        const int t = wave;
        f32x4 ga = (f32x4){0.f, 0.f, 0.f, 0.f};
#pragma unroll
        for (int k0 = 0; k0 < 4; ++k0) {
            const bf16x8 a = *(const bf16x8*)&h_lds[c * 136 + k0 * 32 + g4 * 8];
            const bf16x8 b = *(const bf16x8*)&Wpk[((t * 4 + k0) * 64 + lane) * 8];
            ga = __builtin_amdgcn_mfma_f32_16x16x32_bf16(a, b, ga, 0, 0, 0);
        }
        const float bb = biasg[t * 16 + c];
#pragma unroll
        for (int j = 0; j < 4; ++j)
            gate_lds[(t >> 2) * 1088 + (g4 * 4 + j) * 68 + (t & 3) * 16 + c] = ga[j] + bb;
    }
    __syncthreads();
    // ---- LSTM nonlinearity: ht = sig(o)*tanh(sig(i)*tanh(g)) ----
    {
        const int n = tid >> 6, hh = tid & 63;
        const float iv = gate_lds[n * 68 + hh];
        const float gv = gate_lds[1088 + n * 68 + hh];
        const float ov = gate_lds[2176 + n * 68 + hh];
        const float cv = sigf(iv) * tanhf(gv);
        const float htv = sigf(ov) * tanhf(cv);
        __syncthreads();
        h_lds[n * 136 + hh] = bf_rne(htv);   // reuse h_lds (gates consumed h)
    }
    __syncthreads();
    // ---- fc GEMM: waves 0,1 -> out[16 nodes][32] ----
    if (wave < 2) {
        const int t2 = wave;
        f32x4 fa = (f32x4){0.f, 0.f, 0.f, 0.f};
#pragma unroll
        for (int k0 = 0; k0 < 2; ++k0) {
            const bf16x8 a = *(const bf16x8*)&h_lds[c * 136 + k0 * 32 + g4 * 8];
            const bf16x8 b = *(const bf16x8*)&fcb[((t2 * 2 + k0) * 64 + lane) * 8];
            fa = __builtin_amdgcn_mfma_f32_16x16x32_bf16(a, b, fa, 0, 0, 0);
        }
        const float fb = fc_b[t2 * 16 + c];
#pragma unroll
        for (int j = 0; j < 4; ++j)
            out[(p0 + g4 * 4 + j) * 32 + t2 * 16 + c] = fa[j] + fb;
    }
}

extern "C" void kernel_launch(void* const* d_in, const int* in_sizes, int n_in,
                              void* d_out, int out_size, void* d_ws, size_t ws_size,
                              hipStream_t stream) {
    const float* X     = (const float*)d_in[0];
    const int*   adj   = (const int*)d_in[1];
    // d_in[2] temporal_features: unused by the reference
    const float* Wg    = (const float*)d_in[3];
    const float* a_src = (const float*)d_in[4];
    const float* a_dst = (const float*)d_in[5];
    const float* W_ih  = (const float*)d_in[6];
    // d_in[7] W_hh: unused (h0 == 0)
    const float* b_ih  = (const float*)d_in[8];
    const float* b_hh  = (const float*)d_in[9];
    const float* fc_W  = (const float*)d_in[10];
    const float* fc_b  = (const float*)d_in[11];
    float* out = (float*)d_out;

    char* ws = (char*)d_ws;
    unsigned short* whB = (unsigned short*)ws;                       // 1 MB
    float* e1s = (float*)(ws + (1 << 20));                           // 32 KB
    float* e2s = (float*)(ws + (1 << 20) + (32 << 10));              // 32 KB
    float* e1d = (float*)(ws + (1 << 20) + (64 << 10));              // 32 KB
    float* e2d = (float*)(ws + (1 << 20) + (96 << 10));              // 32 KB
    unsigned long long* adjbits = (unsigned long long*)(ws + (1 << 20) + (128 << 10)); // 2 MB
    char* ws2 = ws + (3 << 20) + (128 << 10);
    unsigned short* Wpk = (unsigned short*)ws2;                      // 48 KB
    unsigned short* fcb = (unsigned short*)(ws2 + (48 << 10));       // 4 KB
    float* biasg = (float*)(ws2 + (52 << 10));                       // 768 B

    hipLaunchKernelGGL(prep_all, dim3(1193), dim3(256), 0, stream,
                       X, Wg, a_src, a_dst, adj, W_ih, b_ih, b_hh, fc_W,
                       whB, e1s, e2s, e1d, e2d, adjbits, Wpk, fcb, biasg);
    hipLaunchKernelGGL(gat_attn, dim3(256), dim3(1024), 0, stream,
                       adjbits, whB, e1s, e2s, e1d, e2d, Wpk, fcb, biasg, fc_b, out);
}